// Round 1
// baseline (3009.182 us; speedup 1.0000x reference)
//
#include <hip/hip_runtime.h>
#include <hip/hip_bf16.h>
#include <cstdint>
#include <cstddef>

typedef __attribute__((ext_vector_type(8))) short bf16x8;
typedef __attribute__((ext_vector_type(4))) float f32x4;

#define DEV __device__ __forceinline__

DEV unsigned short f2bf(float f) {
  unsigned int u = __float_as_uint(f);
  return (unsigned short)((u + 0x7fffu + ((u >> 16) & 1u)) >> 16);
}

DEV void gl_lds16(const unsigned short* g, unsigned short* l) {
  __builtin_amdgcn_global_load_lds(
      (__attribute__((address_space(1))) const void*)g,
      (__attribute__((address_space(3))) void*)l, 16, 0, 0);
}

// ---- states fp32 -> bf16 (exact grid: 4096 blocks x 256 thr x 1 float4) ----
__global__ __launch_bounds__(256) void cvt_kernel(const float* __restrict__ src,
                                                  unsigned short* __restrict__ dst) {
  size_t i = (size_t)blockIdx.x * 256 + threadIdx.x;
  float4 v = ((const float4*)src)[i];
  ushort4 o;
  o.x = f2bf(v.x); o.y = f2bf(v.y); o.z = f2bf(v.z); o.w = f2bf(v.w);
  ((ushort4*)dst)[i] = o;
}

// ---- weights: src [nmat][K][1024] f32  ->  dst [nmat][1024][K] bf16 (transpose) ----
__global__ __launch_bounds__(256) void transpose_kernel(const float* __restrict__ src,
                                                        unsigned short* __restrict__ dst,
                                                        int K) {
  __shared__ float tile[64][68];
  const int t = threadIdx.x;
  const int tpm = (K >> 6) * 16;  // 64x64 tiles per matrix
  const int mat = blockIdx.x / tpm;
  const int r = blockIdx.x % tpm;
  const int tk = r >> 4;
  const int tn = r & 15;
  const size_t sbase = (size_t)mat * K * 1024 + (size_t)tk * 64 * 1024 + (size_t)tn * 64;
#pragma unroll
  for (int p = 0; p < 4; ++p) {
    int row = p * 16 + (t >> 4);
    int c4 = (t & 15) * 4;
    float4 v = *(const float4*)&src[sbase + (size_t)row * 1024 + c4];
    *(float4*)&tile[row][c4] = v;
  }
  __syncthreads();
  const size_t dbase = (size_t)mat * 1024 * K + (size_t)tn * 64 * K + (size_t)tk * 64;
#pragma unroll
  for (int p = 0; p < 4; ++p) {
    int n = p * 16 + (t >> 4);
    int k4 = (t & 15) * 4;
    ushort4 o;
    o.x = f2bf(tile[k4 + 0][n]);
    o.y = f2bf(tile[k4 + 1][n]);
    o.z = f2bf(tile[k4 + 2][n]);
    o.w = f2bf(tile[k4 + 3][n]);
    *(ushort4*)&dst[dbase + (size_t)n * K + k4] = o;
  }
}

struct EdgeCfg {
  const unsigned short* xlo;  // A rows (bf16, row-major, stride 1024)
  const unsigned short* xhi;  // second half for concat edge (k >= 1024)
  const unsigned short* wt;   // 5-op group base; op k matrix = wt + k*1024*inlen, layout [1024][inlen]
  int inlen;                  // 1024 or 2048
  int l;                      // layer index into genotype/bs
};
struct NodeArgs {
  EdgeCfg e[6];
  int nedges;
};

// BM=64, BN=128, BK=32. 256 threads = 4 waves, wave-tile 32x64 (2x4 frags of 16x16x32).
template <int FINAL>
__global__ __launch_bounds__(256) void node_kernel(NodeArgs na,
                                                   const float* __restrict__ genotype,
                                                   const float* __restrict__ bs,
                                                   unsigned short* __restrict__ outb,
                                                   float* __restrict__ outf) {
  __shared__ unsigned short As[64 * 32];   // [m][k]
  __shared__ unsigned short Bs[128 * 32];  // [n][k]

  const int t = threadIdx.x;
  const int lane = t & 63;
  const int w = t >> 6;
  const int wm = (w & 1) * 32;
  const int wn = (w >> 1) * 64;
  const int bm = blockIdx.y * 64;
  const int bn = blockIdx.x * 128;
  const int l15 = lane & 15;
  const int l16 = lane >> 4;

  const int arow = t >> 2;       // 0..63
  const int acol = (t & 3) * 8;  // element offset (16B chunks)

  f32x4 sacc[2][4];
#pragma unroll
  for (int mi = 0; mi < 2; ++mi)
#pragma unroll
    for (int ni = 0; ni < 4; ++ni) sacc[mi][ni] = (f32x4){0.f, 0.f, 0.f, 0.f};

  for (int e = 0; e < na.nedges; ++e) {
    const int inlen = na.e[e].inlen;
    const unsigned short* xlo = na.e[e].xlo;
    const unsigned short* xhi = na.e[e].xhi;
    const unsigned short* wt0 = na.e[e].wt;
    const int l = na.e[e].l;
    const int nk = inlen >> 5;
    for (int k5 = 0; k5 < 5; ++k5) {
      const unsigned short* wtk = wt0 + (size_t)k5 * inlen * 1024;
      f32x4 hacc[2][4];
#pragma unroll
      for (int mi = 0; mi < 2; ++mi)
#pragma unroll
        for (int ni = 0; ni < 4; ++ni) hacc[mi][ni] = (f32x4){0.f, 0.f, 0.f, 0.f};

      for (int kt = 0; kt < nk; ++kt) {
        const int k0 = kt << 5;
        __syncthreads();  // protect LDS from previous iteration's readers
        const unsigned short* ax = (k0 < 1024) ? xlo : xhi;
        const int ak = k0 & 1023;
        gl_lds16(ax + (size_t)(bm + arow) * 1024 + ak + acol, As + t * 8);
        const unsigned short* wrow = wtk + (size_t)(bn + arow) * inlen + k0 + acol;
        gl_lds16(wrow, Bs + t * 8);
        gl_lds16(wrow + (size_t)64 * inlen, Bs + 2048 + t * 8);
        __syncthreads();  // compiler drains vmcnt before barrier

        bf16x8 af[2], bfr[4];
#pragma unroll
        for (int mi = 0; mi < 2; ++mi)
          af[mi] = *(const bf16x8*)&As[(wm + mi * 16 + l15) * 32 + l16 * 8];
#pragma unroll
        for (int ni = 0; ni < 4; ++ni)
          bfr[ni] = *(const bf16x8*)&Bs[(wn + ni * 16 + l15) * 32 + l16 * 8];
#pragma unroll
        for (int mi = 0; mi < 2; ++mi)
#pragma unroll
          for (int ni = 0; ni < 4; ++ni)
            hacc[mi][ni] = __builtin_amdgcn_mfma_f32_16x16x32_bf16(af[mi], bfr[ni],
                                                                   hacc[mi][ni], 0, 0, 0);
      }

      // segment epilogue: h = hacc + bias; s += w[l,k5] * act_k5(h)
      const float wlk = genotype[l * 5 + k5];
      const float* bv = bs + ((size_t)l * 5 + k5) * 1024;
#pragma unroll
      for (int ni = 0; ni < 4; ++ni) {
        const float bias = bv[bn + wn + ni * 16 + l15];  // C-frag: col = lane&15
#pragma unroll
        for (int mi = 0; mi < 2; ++mi)
#pragma unroll
          for (int i = 0; i < 4; ++i) {
            float h = hacc[mi][ni][i] + bias;
            float a;
            if (k5 == 0) a = h;
            else if (k5 == 1) a = fmaxf(h, 0.f);
            else if (k5 == 2) a = 1.f - 2.f / (__expf(2.f * h) + 1.f);   // tanh, NaN-free
            else if (k5 == 3) a = 1.f / (1.f + __expf(-h));              // sigmoid
            else a = (h > 0.f) ? h : 0.2f * h;                           // leaky_relu(0.2)
            sacc[mi][ni][i] += wlk * a;
          }
      }
    }
  }

#pragma unroll
  for (int mi = 0; mi < 2; ++mi)
#pragma unroll
    for (int ni = 0; ni < 4; ++ni)
#pragma unroll
      for (int i = 0; i < 4; ++i) {
        const int row = bm + wm + mi * 16 + l16 * 4 + i;  // C-frag: row = (lane>>4)*4 + i
        const int col = bn + wn + ni * 16 + l15;
        if (FINAL)
          outf[(size_t)row * 1024 + col] = sacc[mi][ni][i];
        else
          outb[(size_t)row * 1024 + col] = f2bf(sacc[mi][ni][i]);
      }
}

extern "C" void kernel_launch(void* const* d_in, const int* in_sizes, int n_in,
                              void* d_out, int out_size, void* d_ws, size_t ws_size,
                              hipStream_t stream) {
  const float* s0 = (const float*)d_in[0];
  const float* s1 = (const float*)d_in[1];
  const float* geno = (const float*)d_in[2];
  const float* Ws = (const float*)d_in[3];
  const float* Wb = (const float*)d_in[4];
  const float* bs = (const float*)d_in[5];

  // ws layout (bf16 elems): WsT 70*1M | WbT 20*2M | S0,S1,T0,T1,T2 4M each  => ~260 MiB
  unsigned short* WsT = (unsigned short*)d_ws;
  unsigned short* WbT = WsT + 70ull * 1024 * 1024;
  unsigned short* S0 = WbT + 20ull * 2048 * 1024;
  unsigned short* S1 = S0 + 4096ull * 1024;
  unsigned short* T0 = S1 + 4096ull * 1024;
  unsigned short* T1 = T0 + 4096ull * 1024;
  unsigned short* T2 = T1 + 4096ull * 1024;

  cvt_kernel<<<4096, 256, 0, stream>>>(s0, S0);
  cvt_kernel<<<4096, 256, 0, stream>>>(s1, S1);
  transpose_kernel<<<70 * 256, 256, 0, stream>>>(Ws, WsT, 1024);
  transpose_kernel<<<20 * 512, 256, 0, stream>>>(Wb, WbT, 2048);

  auto SE = [&](const unsigned short* x, int si, int l) {
    EdgeCfg c;
    c.xlo = x; c.xhi = x;
    c.wt = WsT + (size_t)si * 5 * 1024 * 1024;
    c.inlen = 1024; c.l = l;
    return c;
  };
  auto BE = [&](int bi, int l) {
    EdgeCfg c;
    c.xlo = S0; c.xhi = S1;
    c.wt = WbT + (size_t)bi * 5 * 2048 * 1024;
    c.inlen = 2048; c.l = l;
    return c;
  };

  dim3 grid(8, 64);  // N-tiles x M-tiles
  {
    NodeArgs a{}; a.nedges = 3;
    a.e[0] = SE(S0, 0, 0); a.e[1] = SE(S1, 1, 1); a.e[2] = BE(0, 2);
    node_kernel<0><<<grid, 256, 0, stream>>>(a, geno, bs, T0, nullptr);
  }
  {
    NodeArgs a{}; a.nedges = 4;
    a.e[0] = SE(S0, 2, 3); a.e[1] = SE(S1, 3, 4); a.e[2] = BE(1, 5); a.e[3] = SE(T0, 4, 6);
    node_kernel<0><<<grid, 256, 0, stream>>>(a, geno, bs, T1, nullptr);
  }
  {
    NodeArgs a{}; a.nedges = 5;
    a.e[0] = SE(S0, 5, 7); a.e[1] = SE(S1, 6, 8); a.e[2] = BE(2, 9);
    a.e[3] = SE(T0, 7, 10); a.e[4] = SE(T1, 8, 11);
    node_kernel<0><<<grid, 256, 0, stream>>>(a, geno, bs, T2, nullptr);
  }
  {
    NodeArgs a{}; a.nedges = 6;
    a.e[0] = SE(S0, 9, 12); a.e[1] = SE(S1, 10, 13); a.e[2] = BE(3, 14);
    a.e[3] = SE(T0, 11, 15); a.e[4] = SE(T1, 12, 16); a.e[5] = SE(T2, 13, 17);
    node_kernel<1><<<grid, 256, 0, stream>>>(a, geno, bs, nullptr, (float*)d_out);
  }
}

// Round 2
// 2851.137 us; speedup vs baseline: 1.0554x; 1.0554x over previous
//
#include <hip/hip_runtime.h>
#include <hip/hip_bf16.h>
#include <cstdint>
#include <cstddef>

typedef __attribute__((ext_vector_type(8))) short bf16x8;
typedef __attribute__((ext_vector_type(4))) float f32x4;

#define DEV __device__ __forceinline__

DEV unsigned short f2bf(float f) {
  unsigned int u = __float_as_uint(f);
  return (unsigned short)((u + 0x7fffu + ((u >> 16) & 1u)) >> 16);
}

DEV void gl_lds16(const unsigned short* g, unsigned short* l) {
  __builtin_amdgcn_global_load_lds(
      (__attribute__((address_space(1))) const void*)g,
      (__attribute__((address_space(3))) void*)l, 16, 0, 0);
}

// ---- states fp32 -> bf16 (exact grid: 4096 blocks x 256 thr x 1 float4) ----
__global__ __launch_bounds__(256) void cvt_kernel(const float* __restrict__ src,
                                                  unsigned short* __restrict__ dst) {
  size_t i = (size_t)blockIdx.x * 256 + threadIdx.x;
  float4 v = ((const float4*)src)[i];
  ushort4 o;
  o.x = f2bf(v.x); o.y = f2bf(v.y); o.z = f2bf(v.z); o.w = f2bf(v.w);
  ((ushort4*)dst)[i] = o;
}

// ---- zero an fp32 buffer (grid 4096 x 256 x float4 = 4M floats) ----
__global__ __launch_bounds__(256) void zero_kernel(float* __restrict__ p) {
  size_t i = (size_t)blockIdx.x * 256 + threadIdx.x;
  ((float4*)p)[i] = make_float4(0.f, 0.f, 0.f, 0.f);
}

// ---- S fp32 -> bf16 state, and re-zero S for the next node ----
__global__ __launch_bounds__(256) void cvtzero_kernel(float* __restrict__ s,
                                                      unsigned short* __restrict__ dst) {
  size_t i = (size_t)blockIdx.x * 256 + threadIdx.x;
  float4 v = ((float4*)s)[i];
  ushort4 o;
  o.x = f2bf(v.x); o.y = f2bf(v.y); o.z = f2bf(v.z); o.w = f2bf(v.w);
  ((ushort4*)dst)[i] = o;
  ((float4*)s)[i] = make_float4(0.f, 0.f, 0.f, 0.f);
}

// ---- weights: src [nmat][K][1024] f32  ->  dst [nmat][1024][K] bf16 (transpose) ----
__global__ __launch_bounds__(256) void transpose_kernel(const float* __restrict__ src,
                                                        unsigned short* __restrict__ dst,
                                                        int K) {
  __shared__ float tile[64][68];
  const int t = threadIdx.x;
  const int tpm = (K >> 6) * 16;  // 64x64 tiles per matrix
  const int mat = blockIdx.x / tpm;
  const int r = blockIdx.x % tpm;
  const int tk = r >> 4;
  const int tn = r & 15;
  const size_t sbase = (size_t)mat * K * 1024 + (size_t)tk * 64 * 1024 + (size_t)tn * 64;
#pragma unroll
  for (int p = 0; p < 4; ++p) {
    int row = p * 16 + (t >> 4);
    int c4 = (t & 15) * 4;
    float4 v = *(const float4*)&src[sbase + (size_t)row * 1024 + c4];
    *(float4*)&tile[row][c4] = v;
  }
  __syncthreads();
  const size_t dbase = (size_t)mat * 1024 * K + (size_t)tn * 64 * K + (size_t)tk * 64;
#pragma unroll
  for (int p = 0; p < 4; ++p) {
    int n = p * 16 + (t >> 4);
    int k4 = (t & 15) * 4;
    ushort4 o;
    o.x = f2bf(tile[k4 + 0][n]);
    o.y = f2bf(tile[k4 + 1][n]);
    o.z = f2bf(tile[k4 + 2][n]);
    o.w = f2bf(tile[k4 + 3][n]);
    *(ushort4*)&dst[dbase + (size_t)n * K + k4] = o;
  }
}

struct EdgeCfg {
  const unsigned short* xlo;  // A rows (bf16, row-major, stride 1024)
  const unsigned short* xhi;  // second half for concat edge (k >= 1024)
  const unsigned short* wt;   // 5-op group base; op k matrix at wt + k*inlen*1024, layout [1024][inlen]
  int inlen;                  // 1024 or 2048
  int l;                      // layer index into genotype/bs
};
struct NodeArgs {
  EdgeCfg e[6];
  int nedges;
};

// Op-split GEMM: grid (8 bn, 32 bm, 5 op). BM=BN=128, BK=32, 4 waves of 64x64
// (4x4 frags of 16x16x32). Each block computes sum over edges of
// w[l,op]*act_op(x_e W_e,op + b) for its tile, then atomicAdds into sout (f32).
__global__ __launch_bounds__(256) void node_gemm(NodeArgs na,
                                                 const float* __restrict__ genotype,
                                                 const float* __restrict__ bs,
                                                 float* __restrict__ sout) {
  __shared__ unsigned short As[128 * 32];
  __shared__ unsigned short Bs[128 * 32];

  const int t = threadIdx.x;
  const int lane = t & 63;
  const int w = t >> 6;
  const int wm = (w & 1) * 64;
  const int wn = (w >> 1) * 64;
  const int bn = blockIdx.x * 128;
  const int bm = blockIdx.y * 128;
  const int kop = blockIdx.z;  // which of the 5 candidate ops (uniform per block)
  const int l15 = lane & 15;
  const int l16 = lane >> 4;

  const int srow = t >> 2;       // 0..63 staging row
  const int scol = (t & 3) * 8;  // staging k-offset (shorts; 16B chunks)

  f32x4 sacc[4][4];
#pragma unroll
  for (int mi = 0; mi < 4; ++mi)
#pragma unroll
    for (int ni = 0; ni < 4; ++ni) sacc[mi][ni] = (f32x4){0.f, 0.f, 0.f, 0.f};

  for (int e = 0; e < na.nedges; ++e) {
    const int inlen = na.e[e].inlen;
    const unsigned short* xlo = na.e[e].xlo;
    const unsigned short* xhi = na.e[e].xhi;
    const unsigned short* wtk = na.e[e].wt + (size_t)kop * inlen * 1024;
    const int l = na.e[e].l;
    const int nk = inlen >> 5;

    f32x4 hacc[4][4];
#pragma unroll
    for (int mi = 0; mi < 4; ++mi)
#pragma unroll
      for (int ni = 0; ni < 4; ++ni) hacc[mi][ni] = (f32x4){0.f, 0.f, 0.f, 0.f};

    for (int kt = 0; kt < nk; ++kt) {
      const int k0 = kt << 5;
      __syncthreads();  // protect LDS from previous iteration's readers
      const unsigned short* ax = (k0 < 1024) ? xlo : xhi;
      const int ak = k0 & 1023;
      gl_lds16(ax + (size_t)(bm + srow) * 1024 + ak + scol, As + t * 8);
      gl_lds16(ax + (size_t)(bm + 64 + srow) * 1024 + ak + scol, As + 2048 + t * 8);
      const unsigned short* wr = wtk + (size_t)(bn + srow) * inlen + k0 + scol;
      gl_lds16(wr, Bs + t * 8);
      gl_lds16(wr + (size_t)64 * inlen, Bs + 2048 + t * 8);
      __syncthreads();  // compiler drains vmcnt before barrier

      bf16x8 af[4], bfr[4];
#pragma unroll
      for (int mi = 0; mi < 4; ++mi)
        af[mi] = *(const bf16x8*)&As[(wm + mi * 16 + l15) * 32 + l16 * 8];
#pragma unroll
      for (int ni = 0; ni < 4; ++ni)
        bfr[ni] = *(const bf16x8*)&Bs[(wn + ni * 16 + l15) * 32 + l16 * 8];
#pragma unroll
      for (int mi = 0; mi < 4; ++mi)
#pragma unroll
        for (int ni = 0; ni < 4; ++ni)
          hacc[mi][ni] = __builtin_amdgcn_mfma_f32_16x16x32_bf16(af[mi], bfr[ni],
                                                                 hacc[mi][ni], 0, 0, 0);
    }

    // edge epilogue: h = hacc + bias; sacc += w[l,kop] * act_kop(h)  (kop uniform)
    const float wlk = genotype[l * 5 + kop];
    const float* bv = bs + ((size_t)l * 5 + kop) * 1024;
#pragma unroll
    for (int ni = 0; ni < 4; ++ni) {
      const float bias = bv[bn + wn + ni * 16 + l15];  // C-frag: col = lane&15
#pragma unroll
      for (int mi = 0; mi < 4; ++mi)
#pragma unroll
        for (int i = 0; i < 4; ++i) {
          float h = hacc[mi][ni][i] + bias;
          float a;
          if (kop == 0) a = h;
          else if (kop == 1) a = fmaxf(h, 0.f);
          else if (kop == 2) a = 1.f - 2.f / (__expf(2.f * h) + 1.f);   // tanh, NaN-free
          else if (kop == 3) a = 1.f / (1.f + __expf(-h));              // sigmoid
          else a = (h > 0.f) ? h : 0.2f * h;                            // leaky_relu(0.2)
          sacc[mi][ni][i] += wlk * a;
        }
    }
  }

  // one atomic pass per block: 5 op-blocks reduce into sout
#pragma unroll
  for (int mi = 0; mi < 4; ++mi)
#pragma unroll
    for (int ni = 0; ni < 4; ++ni)
#pragma unroll
      for (int i = 0; i < 4; ++i) {
        const int row = bm + wm + mi * 16 + l16 * 4 + i;  // C-frag: row = (lane>>4)*4 + i
        const int col = bn + wn + ni * 16 + l15;
        unsafeAtomicAdd(&sout[(size_t)row * 1024 + col], sacc[mi][ni][i]);
      }
}

extern "C" void kernel_launch(void* const* d_in, const int* in_sizes, int n_in,
                              void* d_out, int out_size, void* d_ws, size_t ws_size,
                              hipStream_t stream) {
  const float* s0 = (const float*)d_in[0];
  const float* s1 = (const float*)d_in[1];
  const float* geno = (const float*)d_in[2];
  const float* Ws = (const float*)d_in[3];
  const float* Wb = (const float*)d_in[4];
  const float* bs = (const float*)d_in[5];

  // ws layout: WsT 70M bf16 | WbT 40M bf16 | S0,S1,T0,T1,T2 4M bf16 each | S 4M f32
  unsigned short* WsT = (unsigned short*)d_ws;
  unsigned short* WbT = WsT + 70ull * 1024 * 1024;
  unsigned short* S0 = WbT + 20ull * 2048 * 1024;
  unsigned short* S1 = S0 + 4096ull * 1024;
  unsigned short* T0 = S1 + 4096ull * 1024;
  unsigned short* T1 = T0 + 4096ull * 1024;
  unsigned short* T2 = T1 + 4096ull * 1024;
  float* S = (float*)(T2 + 4096ull * 1024);

  cvt_kernel<<<4096, 256, 0, stream>>>(s0, S0);
  cvt_kernel<<<4096, 256, 0, stream>>>(s1, S1);
  zero_kernel<<<4096, 256, 0, stream>>>(S);
  zero_kernel<<<4096, 256, 0, stream>>>((float*)d_out);
  transpose_kernel<<<70 * 256, 256, 0, stream>>>(Ws, WsT, 1024);
  transpose_kernel<<<20 * 512, 256, 0, stream>>>(Wb, WbT, 2048);

  auto SE = [&](const unsigned short* x, int si, int l) {
    EdgeCfg c;
    c.xlo = x; c.xhi = x;
    c.wt = WsT + (size_t)si * 5 * 1024 * 1024;
    c.inlen = 1024; c.l = l;
    return c;
  };
  auto BE = [&](int bi, int l) {
    EdgeCfg c;
    c.xlo = S0; c.xhi = S1;
    c.wt = WbT + (size_t)bi * 5 * 2048 * 1024;
    c.inlen = 2048; c.l = l;
    return c;
  };

  dim3 grid(8, 32, 5);  // bn x bm x op
  {
    NodeArgs a{}; a.nedges = 3;
    a.e[0] = SE(S0, 0, 0); a.e[1] = SE(S1, 1, 1); a.e[2] = BE(0, 2);
    node_gemm<<<grid, 256, 0, stream>>>(a, geno, bs, S);
    cvtzero_kernel<<<4096, 256, 0, stream>>>(S, T0);
  }
  {
    NodeArgs a{}; a.nedges = 4;
    a.e[0] = SE(S0, 2, 3); a.e[1] = SE(S1, 3, 4); a.e[2] = BE(1, 5); a.e[3] = SE(T0, 4, 6);
    node_gemm<<<grid, 256, 0, stream>>>(a, geno, bs, S);
    cvtzero_kernel<<<4096, 256, 0, stream>>>(S, T1);
  }
  {
    NodeArgs a{}; a.nedges = 5;
    a.e[0] = SE(S0, 5, 7); a.e[1] = SE(S1, 6, 8); a.e[2] = BE(2, 9);
    a.e[3] = SE(T0, 7, 10); a.e[4] = SE(T1, 8, 11);
    node_gemm<<<grid, 256, 0, stream>>>(a, geno, bs, S);
    cvtzero_kernel<<<4096, 256, 0, stream>>>(S, T2);
  }
  {
    NodeArgs a{}; a.nedges = 6;
    a.e[0] = SE(S0, 9, 12); a.e[1] = SE(S1, 10, 13); a.e[2] = BE(3, 14);
    a.e[3] = SE(T0, 11, 15); a.e[4] = SE(T1, 12, 16); a.e[5] = SE(T2, 13, 17);
    node_gemm<<<grid, 256, 0, stream>>>(a, geno, bs, (float*)d_out);
  }
}